// Round 1
// baseline (532.146 us; speedup 1.0000x reference)
//
#include <hip/hip_runtime.h>

#define NN 8192
#define FF 256
#define BK 256
#define PST 264   // P LDS row stride in halves (256 + 8 pad)

typedef _Float16 h8 __attribute__((ext_vector_type(8)));
typedef _Float16 h4 __attribute__((ext_vector_type(4)));
typedef float    f4 __attribute__((ext_vector_type(4)));
typedef int      i4v __attribute__((ext_vector_type(4)));

// ---------------- Kernel 1: Wh fp32 -> (Wh f16 row-major) + s1 + s2 ----------
// grid 512 x 256 thr; block handles 16 rows of h. fp32 vector FMA (no fp32 MFMA).
__global__ __launch_bounds__(256) void k_wh(
    const float* __restrict__ h, const float* __restrict__ W,
    const float* __restrict__ a, _Float16* __restrict__ whr,
    float* __restrict__ s1, float* __restrict__ s2) {
  __shared__ float hs[16 * 256];
  const int t = threadIdx.x;
  const int r0 = blockIdx.x * 16;
#pragma unroll
  for (int i = 0; i < 4; ++i) {
    int idx = i * 1024 + t * 4;
    *(f4*)&hs[idx] = *(const f4*)&h[(size_t)r0 * 256 + idx];
  }
  __syncthreads();
  const int lane = t & 63;
  const int wv = t >> 6;
  const int rg = wv * 4;        // 4 rows per wave
  const int c4 = lane * 4;      // 4 cols per lane
  float acc[4][4];
#pragma unroll
  for (int i = 0; i < 4; ++i)
#pragma unroll
    for (int k = 0; k < 4; ++k) acc[i][k] = 0.f;
  for (int f = 0; f < 256; f += 4) {
    f4 w0 = *(const f4*)&W[(f + 0) * 256 + c4];
    f4 w1 = *(const f4*)&W[(f + 1) * 256 + c4];
    f4 w2 = *(const f4*)&W[(f + 2) * 256 + c4];
    f4 w3 = *(const f4*)&W[(f + 3) * 256 + c4];
#pragma unroll
    for (int i = 0; i < 4; ++i) {
      f4 hv = *(const f4*)&hs[(rg + i) * 256 + f];   // wave-uniform: LDS broadcast
#pragma unroll
      for (int k = 0; k < 4; ++k)
        acc[i][k] += hv[0] * w0[k] + hv[1] * w1[k] + hv[2] * w2[k] + hv[3] * w3[k];
    }
  }
  float a1v[4], a2v[4];
#pragma unroll
  for (int k = 0; k < 4; ++k) { a1v[k] = a[c4 + k]; a2v[k] = a[256 + c4 + k]; }
#pragma unroll
  for (int i = 0; i < 4; ++i) {
    h4 hh;
    float p1 = 0.f, p2 = 0.f;
#pragma unroll
    for (int k = 0; k < 4; ++k) {
      hh[k] = (_Float16)acc[i][k];
      p1 += acc[i][k] * a1v[k];
      p2 += acc[i][k] * a2v[k];
    }
    *(h4*)&whr[(size_t)(r0 + rg + i) * 256 + c4] = hh;
#pragma unroll
    for (int off = 32; off; off >>= 1) {
      p1 += __shfl_xor(p1, off);
      p2 += __shfl_xor(p2, off);
    }
    if (lane == 0) { s1[r0 + rg + i] = p1; s2[r0 + rg + i] = p2; }
  }
}

// ---------------- Kernel 2: transpose Wh f16 [N][F] -> [F][N]; + s2max -------
__global__ __launch_bounds__(256) void k_tr(
    const _Float16* __restrict__ whr, _Float16* __restrict__ wht,
    const float* __restrict__ s2, float* __restrict__ s2maxp) {
  __shared__ _Float16 tt[64 * 65];
  const int t = threadIdx.x;
  const int tr0 = blockIdx.x * 64;   // N-dim tile
  const int tc0 = blockIdx.y * 64;   // F-dim tile
  {
    const int rr = t >> 4;
    const int c4 = (t & 15) * 4;
#pragma unroll
    for (int i = 0; i < 4; ++i) {
      int r = rr + i * 16;
      h4 v = *(const h4*)&whr[(size_t)(tr0 + r) * 256 + tc0 + c4];
#pragma unroll
      for (int k = 0; k < 4; ++k) tt[(c4 + k) * 65 + r] = v[k];
    }
  }
  __syncthreads();
  {
    const int r4 = (t & 15) * 4;
    const int cc = t >> 4;
#pragma unroll
    for (int i = 0; i < 4; ++i) {
      int c = cc + i * 16;
      h4 v;
#pragma unroll
      for (int k = 0; k < 4; ++k) v[k] = tt[c * 65 + r4 + k];
      *(h4*)&wht[(size_t)(tc0 + c) * NN + tr0 + r4] = v;
    }
  }
  // one block also computes max(s2) (s2 was fully written by k_wh)
  if (blockIdx.x == 0 && blockIdx.y == 0) {
    float mx = -1e30f;
    for (int i = t; i < NN; i += 256) mx = fmaxf(mx, s2[i]);
#pragma unroll
    for (int off = 32; off; off >>= 1) mx = fmaxf(mx, __shfl_xor(mx, off));
    __shared__ float wmx[4];
    if ((t & 63) == 0) wmx[t >> 6] = mx;
    __syncthreads();
    if (t == 0) *s2maxp = fmaxf(fmaxf(wmx[0], wmx[1]), fmaxf(wmx[2], wmx[3]));
  }
}

// ---------------- Kernel 3: fused masked-softmax attention -------------------
// grid 256 x 512 thr. Block = 32 rows; wave w scores rows 4w..4w+3, owns output
// cols [32w,32w+32). Static per-row shift m_r = leaky(s1_r + max(s2)) keeps
// P=exp(score-m_r) in (0,1] -> safe in f16, no online-softmax rescaling needed.
__global__ __launch_bounds__(512) void k_gat(
    const int* __restrict__ adj, const _Float16* __restrict__ wht,
    const float* __restrict__ s1g, const float* __restrict__ s2g,
    const float* __restrict__ s2maxp, float* __restrict__ out) {
  __shared__ _Float16 plds[2][32 * PST];
  __shared__ float lsh[32];
  const int t = threadIdx.x;
  const int lane = t & 63;
  const int wv = t >> 6;          // 0..7
  const int r0 = blockIdx.x * 32;
  const int q = lane >> 4;
  const int m16 = lane & 15;
  const int nb = wv * 32;         // wave's output-col base
  const int col0 = lane * 4;      // lane's j-offset within a tile

  const float s2m = *s2maxp;
  float s1v[4], mi[4];
#pragma unroll
  for (int i = 0; i < 4; ++i) {
    s1v[i] = s1g[r0 + wv * 4 + i];
    float y = s1v[i] + s2m;
    mi[i] = fmaxf(y, 0.2f * y);   // row-wise upper bound on all scores
  }

  f4 accf[2][2];
#pragma unroll
  for (int i = 0; i < 2; ++i)
#pragma unroll
    for (int j = 0; j < 2; ++j)
#pragma unroll
      for (int e = 0; e < 4; ++e) accf[i][j][e] = 0.f;
  float lsum[4] = {0.f, 0.f, 0.f, 0.f};

  i4v adjA[4], adjB[4];
  f4 s2A, s2B;
#pragma unroll
  for (int i = 0; i < 4; ++i) {
    adjA[i] = __builtin_nontemporal_load(
        (const i4v*)&adj[(size_t)(r0 + wv * 4 + i) * NN + 0 * BK + col0]);
    adjB[i] = __builtin_nontemporal_load(
        (const i4v*)&adj[(size_t)(r0 + wv * 4 + i) * NN + 1 * BK + col0]);
  }
  s2A = *(const f4*)&s2g[0 * BK + col0];
  s2B = *(const f4*)&s2g[1 * BK + col0];

  auto step = [&](int tt, int lb, i4v (&adjc)[4], f4& s2c) {
    const int j0 = tt * BK;
    float pv[4][4];
#pragma unroll
    for (int i = 0; i < 4; ++i) {
#pragma unroll
      for (int k = 0; k < 4; ++k) {
        float x = s1v[i] + s2c[k];
        float e = fmaxf(x, 0.2f * x);           // leaky_relu(x), slope 0.2
        float p = (adjc[i][k] > 0) ? __expf(e - mi[i]) : 0.0f;
        pv[i][k] = p;
        lsum[i] += p;
      }
    }
    // distance-2 prefetch into the just-consumed buffer
    if (tt + 2 < NN / BK) {
      const int j2 = (tt + 2) * BK;
#pragma unroll
      for (int i = 0; i < 4; ++i)
        adjc[i] = __builtin_nontemporal_load(
            (const i4v*)&adj[(size_t)(r0 + wv * 4 + i) * NN + j2 + col0]);
      s2c = *(const f4*)&s2g[j2 + col0];
    }
#pragma unroll
    for (int i = 0; i < 4; ++i) {
      h4 hp;
#pragma unroll
      for (int k = 0; k < 4; ++k) hp[k] = (_Float16)pv[i][k];
      *(h4*)&plds[lb][(wv * 4 + i) * PST + col0] = hp;
    }
    __syncthreads();
    const _Float16* pb = &plds[lb][0];
#pragma unroll
    for (int kk = 0; kk < 8; ++kk) {
      const int ko = kk * 32 + q * 8;
      h8 a0 = *(const h8*)&pb[m16 * PST + ko];
      h8 a1 = *(const h8*)&pb[(16 + m16) * PST + ko];
      h8 b0 = *(const h8*)&wht[(size_t)(nb + m16) * NN + j0 + ko];
      h8 b1 = *(const h8*)&wht[(size_t)(nb + 16 + m16) * NN + j0 + ko];
      accf[0][0] = __builtin_amdgcn_mfma_f32_16x16x32_f16(a0, b0, accf[0][0], 0, 0, 0);
      accf[0][1] = __builtin_amdgcn_mfma_f32_16x16x32_f16(a0, b1, accf[0][1], 0, 0, 0);
      accf[1][0] = __builtin_amdgcn_mfma_f32_16x16x32_f16(a1, b0, accf[1][0], 0, 0, 0);
      accf[1][1] = __builtin_amdgcn_mfma_f32_16x16x32_f16(a1, b1, accf[1][1], 0, 0, 0);
    }
  };

  for (int it = 0; it < NN / BK / 2; ++it) {
    step(2 * it + 0, 0, adjA, s2A);
    step(2 * it + 1, 1, adjB, s2B);
  }

  // reduce softmax denominators (one reduction total, not per tile)
#pragma unroll
  for (int i = 0; i < 4; ++i) {
    float v = lsum[i];
#pragma unroll
    for (int off = 32; off; off >>= 1) v += __shfl_xor(v, off);
    if (lane == 0) lsh[wv * 4 + i] = v;
  }
  __syncthreads();

  // epilogue: out = elu(acc / l). C layout: col=lane&15, row=(lane>>4)*4+reg.
#pragma unroll
  for (int mt = 0; mt < 2; ++mt) {
#pragma unroll
    for (int v_ = 0; v_ < 4; ++v_) {
      const int row = mt * 16 + q * 4 + v_;
      const float linv = 1.0f / lsh[row];
#pragma unroll
      for (int nt = 0; nt < 2; ++nt) {
        float x = accf[mt][nt][v_] * linv;
        out[(size_t)(r0 + row) * FF + nb + nt * 16 + m16] =
            (x > 0.f) ? x : (__expf(x) - 1.0f);
      }
    }
  }
}

extern "C" void kernel_launch(void* const* d_in, const int* in_sizes, int n_in,
                              void* d_out, int out_size, void* d_ws, size_t ws_size,
                              hipStream_t stream) {
  const float* h   = (const float*)d_in[0];
  const int*   adj = (const int*)d_in[1];
  const float* W   = (const float*)d_in[2];
  const float* a   = (const float*)d_in[3];
  float* out = (float*)d_out;

  char* ws = (char*)d_ws;
  _Float16* whr = (_Float16*)ws;                          // 4 MB: Wh f16 [N][F]
  _Float16* wht = (_Float16*)(ws + 4u * 1024 * 1024);     // 4 MB: Wh f16 [F][N]
  float* s1     = (float*)(ws + 8u * 1024 * 1024);        // 32 KB
  float* s2     = (float*)(ws + 8u * 1024 * 1024 + 32768);// 32 KB
  float* s2max  = (float*)(ws + 8u * 1024 * 1024 + 65536);// 4 B

  k_wh<<<512, 256, 0, stream>>>(h, W, a, whr, s1, s2);
  k_tr<<<dim3(128, 4), 256, 0, stream>>>(whr, wht, s2, s2max);
  k_gat<<<256, 512, 0, stream>>>(adj, wht, s1, s2, s2max, out);
}